// Round 8
// baseline (257.037 us; speedup 1.0000x reference)
//
#include <hip/hip_runtime.h>
#include <hip/hip_bf16.h>
#include <math.h>

#define NDIM 768
#define NHEADS 12
#define HD 64
#define SEQ 1024
#define BATCH 8
#define MROWS (BATCH * SEQ)          // 8192
#define SQRT_DIM 27.712812921102035f // 1/SCALE_PARAM_INIT
#define LOG2E 1.4426950408889634f

typedef unsigned short u16;
typedef unsigned int u32;
typedef __attribute__((ext_vector_type(8))) short short8;   // 8 bf16 = 4 VGPRs
typedef __attribute__((ext_vector_type(4))) short bf16x4;   // 4 bf16 = 2 VGPRs
typedef __attribute__((ext_vector_type(4))) float f32x4;
typedef __attribute__((ext_vector_type(16))) float f32x16;

#define MFMA16(a, b, c) __builtin_amdgcn_mfma_f32_16x16x32_bf16(a, b, c, 0, 0, 0)
#define MFMA32(a, b, c) __builtin_amdgcn_mfma_f32_32x32x16_bf16(a, b, c, 0, 0, 0)

__device__ inline u16 f2bf(float f) {
    __hip_bfloat16 h = __float2bfloat16(f);
    return *reinterpret_cast<u16*>(&h);
}
__device__ inline float bf2f(u16 u) {
    u32 w = ((u32)u) << 16;
    return __builtin_bit_cast(float, w);
}

// async 16B global->LDS. LDS dest is wave-uniform base; HW adds lane*16.
__device__ inline void gl2lds16(const void* g, void* l) {
    __builtin_amdgcn_global_load_lds((const __attribute__((address_space(1))) void*)g,
                                     (__attribute__((address_space(3))) void*)l, 16, 0, 0);
}

// ---------------------------------------------------------------------------
// One fused cast kernel: x (6144 blocks) + Wq/Wk/Wv -> Wqkv, Wo -> Wob.
// ---------------------------------------------------------------------------
__global__ __launch_bounds__(256) void castall(const float* __restrict__ x,
                                               const float* __restrict__ Wq,
                                               const float* __restrict__ Wk,
                                               const float* __restrict__ Wv,
                                               const float* __restrict__ Wo,
                                               u16* __restrict__ xb,
                                               u16* __restrict__ Wqkv,
                                               u16* __restrict__ Wob) {
    const int WB = (NDIM * NDIM) / 1024; // 576 blocks per weight
    int blk = blockIdx.x;
    const float* s;
    u16* d;
    int base;
    if (blk < 6144) {
        s = x; d = xb; base = blk * 1024;
    } else {
        int wsel = (blk - 6144) / WB, r = (blk - 6144) % WB;
        base = r * 1024;
        if (wsel == 0)      { s = Wq; d = Wqkv; }
        else if (wsel == 1) { s = Wk; d = Wqkv + NDIM * NDIM; }
        else if (wsel == 2) { s = Wv; d = Wqkv + 2 * NDIM * NDIM; }
        else                { s = Wo; d = Wob; }
    }
    int i = base + threadIdx.x * 4;
    float4 v = *(const float4*)(s + i);
    d[i] = f2bf(v.x); d[i + 1] = f2bf(v.y); d[i + 2] = f2bf(v.z); d[i + 3] = f2bf(v.w);
}

// ---------------------------------------------------------------------------
// bf16 MFMA GEMM: C = A[M,768] @ B[N,768]^T, fp32 accum. 128x128 tile,
// BK=64 (12 barrier-drain events for K=768 instead of 24), 4 waves (2x2 of
// 64x64). Chunk-transposed LDS (slot = kc*128+row, kc = 16B chunk 0..7);
// fragment reads conflict-free (measured 0).
// 1D grid with XCD-stripe swizzle: blk&7 = XCD, each XCD owns a contiguous
// 8-y-tile (1024-row) M-stripe -> per-XCD L2 working set ~1.6 MB A + B.
// EPI 0: fp32 row-major C.
// EPI 2: fused QKV epilogue (N=2304): per-64-col head group —
//   groups 0..11  = q: cosine-norm + s_eff*8*log2e -> Qdst [b,h,tok,64]
//   groups 12..23 = k: cosine-norm + s_eff         -> Kdst [b,h,tok,64]
//   groups 24..35 = v: bf16 transposed             -> C as Vt [b,h,d,tok]
// ---------------------------------------------------------------------------
template <int EPI>
__global__ __launch_bounds__(256) void gemm_bf16(const u16* __restrict__ A,
                                                 const u16* __restrict__ B,
                                                 void* __restrict__ C, int N,
                                                 const float* __restrict__ s_qk,
                                                 u16* __restrict__ Qdst,
                                                 u16* __restrict__ Kdst,
                                                 int NX) {
    constexpr int K = NDIM;
    __shared__ __align__(16) u16 As[1024 * 8]; // 1024 slots x 16B = 16 KB
    __shared__ __align__(16) u16 Bs[1024 * 8];
    const int t = threadIdx.x;
    const int wave = t >> 6, lane = t & 63;
    const int quad = lane >> 4, l16 = lane & 15;
    const int wx = (wave & 1) * 64, wy = (wave >> 1) * 64;
    // XCD-stripe mapping: 64 y-tiles = 8 per XCD
    const int blk = blockIdx.x;
    const int xcd = blk & 7, local = blk >> 3;
    const int bm = (xcd * 8 + local / NX) * 128;
    const int bn = (local % NX) * 128;

    f32x4 acc[4][4];
#pragma unroll
    for (int i = 0; i < 4; ++i)
#pragma unroll
        for (int j = 0; j < 4; ++j) acc[i][j] = (f32x4){0.f, 0.f, 0.f, 0.f};

    for (int k0 = 0; k0 < K; k0 += 64) {
        __syncthreads();
#pragma unroll
        for (int it = 0; it < 4; ++it) {
            const int cb = it * 256 + wave * 64; // slot base (64-aligned)
            const int kc = cb >> 7;              // 16B chunk 0..7
            const int row = (cb & 127) + lane;
            gl2lds16(A + (size_t)(bm + row) * K + k0 + kc * 8, (char*)As + cb * 16);
            gl2lds16(B + (size_t)(bn + row) * K + k0 + kc * 8, (char*)Bs + cb * 16);
        }
        asm volatile("s_waitcnt vmcnt(0)" ::: "memory");
        __syncthreads();

#pragma unroll
        for (int kk = 0; kk < 2; ++kk) {
            short8 af[4], bf[4];
#pragma unroll
            for (int i = 0; i < 4; ++i)
                af[i] = *(const short8*)&As[((kk * 4 + quad) * 128 + wy + i * 16 + l16) * 8];
#pragma unroll
            for (int j = 0; j < 4; ++j)
                bf[j] = *(const short8*)&Bs[((kk * 4 + quad) * 128 + wx + j * 16 + l16) * 8];
#pragma unroll
            for (int i = 0; i < 4; ++i)
#pragma unroll
                for (int j = 0; j < 4; ++j) acc[i][j] = MFMA16(af[i], bf[j], acc[i][j]);
        }
    }

    if constexpr (EPI == 0) {
#pragma unroll
        for (int i = 0; i < 4; ++i)
#pragma unroll
            for (int j = 0; j < 4; ++j)
#pragma unroll
                for (int r = 0; r < 4; ++r) {
                    const int row = bm + wy + i * 16 + quad * 4 + r;
                    const int col = bn + wx + j * 16 + l16;
                    ((float*)C)[(size_t)row * N + col] = acc[i][j][r];
                }
    } else {
        const int cg = (bn + wx) >> 6; // 0..35
        if (cg >= 2 * NHEADS) {
            // V path: transposed bf16 write into Vt = C
            const int h = cg - 2 * NHEADS;
#pragma unroll
            for (int i = 0; i < 4; ++i)
#pragma unroll
                for (int j = 0; j < 4; ++j)
#pragma unroll
                    for (int r = 0; r < 4; ++r) {
                        const int row = bm + wy + i * 16 + quad * 4 + r; // token
                        const int dd = j * 16 + l16;
                        const int b = row >> 10, n = row & 1023;
                        ((u16*)C)[(((size_t)(b * NHEADS + h) * HD + dd) << 10) + n] =
                            f2bf(acc[i][j][r]);
                    }
        } else {
            const bool isq = cg < NHEADS;
            const int h = isq ? cg : cg - NHEADS;
            u16* dst = isq ? Qdst : Kdst;
            const float ex = isq ? 8.f * LOG2E : 1.f;
            float sq[4];
#pragma unroll
            for (int j = 0; j < 4; ++j)
                sq[j] = s_qk[h * HD + j * 16 + l16] * SQRT_DIM * ex;
#pragma unroll
            for (int i = 0; i < 4; ++i)
#pragma unroll
                for (int r = 0; r < 4; ++r) {
                    float ss = 0.f;
#pragma unroll
                    for (int j = 0; j < 4; ++j) ss += acc[i][j][r] * acc[i][j][r];
                    ss += __shfl_xor(ss, 1, 64);
                    ss += __shfl_xor(ss, 2, 64);
                    ss += __shfl_xor(ss, 4, 64);
                    ss += __shfl_xor(ss, 8, 64);
                    float inv = 1.f / fmaxf(sqrtf(ss), 1e-6f);
                    const int row = bm + wy + i * 16 + quad * 4 + r;
                    const int b = row >> 10, tok = row & 1023;
                    u16* o = dst + ((size_t)(b * NHEADS + h) * SEQ + tok) * HD;
#pragma unroll
                    for (int j = 0; j < 4; ++j)
                        o[j * 16 + l16] = f2bf(acc[i][j][r] * sq[j] * inv);
                }
        }
    }
}

// ---------------------------------------------------------------------------
// MFMA flash attention, 32x32x16, no-max softmax. 256 threads = 4 waves;
// each wave owns 32 queries -> block = 128 queries; streams 64-key tiles.
//   S^T = MFMA(A=K, B=Q): D col = query, consecutive regs = consecutive keys.
//   O^T = MFMA(A=V^T, B=P).
// P buffer: row stride 64 u16 (128 B), XOR-swizzled at 8B-unit granularity
// (phys_unit = u ^ (row & 15)) -> b64 writes and reads conflict-free.
// Qh/Kh: [b,h,tok,64] bf16 (q pre-scaled by 8*log2e), Vt: [b,h,d,tok] bf16.
// l accumulated from bf16-rounded p (numerator/denominator errors cancel).
// ---------------------------------------------------------------------------
__global__ __launch_bounds__(256) void attn_mfma(const u16* __restrict__ Qh,
                                                 const u16* __restrict__ Kh,
                                                 const u16* __restrict__ Vt,
                                                 u16* __restrict__ AO) {
    __shared__ __align__(16) u16 Ks[512 * 8];   // slot = dimchunk*64 + key
    __shared__ __align__(16) u16 Vs[512 * 8];   // slot = keychunk*64 + d
    __shared__ __align__(16) u16 Ps[4 * 32 * 64]; // [wave][qrow][64], swizzled

    const int t = threadIdx.x;
    const int wave = t >> 6, lane = t & 63;
    const int l31 = lane & 31, half = lane >> 5;
    const int b = blockIdx.z, h = blockIdx.y, q0 = blockIdx.x * 128;
    const int bh = b * NHEADS + h;
    const u16* Kb = Kh + (size_t)bh * SEQ * HD;
    const u16* Vb = Vt + (size_t)bh * HD * SEQ;
    const int qb = q0 + wave * 32;
    const int pbase = wave * 2048 + l31 * 64; // this lane's P row (u16 idx)
    const int sw = (l31 & 15);                // XOR key for 8B units

    // Q fragments (B-operand: n = query = l31, k = tt*16 + half*8 + j)
    short8 qf[4];
#pragma unroll
    for (int tt = 0; tt < 4; ++tt)
        qf[tt] = *(const short8*)(Qh + ((size_t)bh * SEQ + qb + l31) * HD +
                                  tt * 16 + half * 8);

    f32x16 o[2]; // [d-tile]
#pragma unroll
    for (int dt = 0; dt < 2; ++dt)
#pragma unroll
        for (int r = 0; r < 16; ++r) o[dt][r] = 0.f;
    float lp = 0.f;

    for (int j0 = 0; j0 < SEQ; j0 += 64) {
        __syncthreads();
#pragma unroll
        for (int it = 0; it < 2; ++it) {
            const int cb = it * 256 + wave * 64; // slot base, wave-uniform
            const int c8 = cb >> 6;              // chunk index 0..7
            gl2lds16(Kb + (size_t)(j0 + lane) * HD + c8 * 8, (char*)Ks + cb * 16);
            gl2lds16(Vb + (size_t)lane * SEQ + j0 + c8 * 8, (char*)Vs + cb * 16);
        }
        asm volatile("s_waitcnt vmcnt(0)" ::: "memory");
        __syncthreads();

        // ---- S^T phase: 64 keys x 32 queries ----
#pragma unroll
        for (int kt = 0; kt < 2; ++kt) {
            f32x16 sa;
#pragma unroll
            for (int r = 0; r < 16; ++r) sa[r] = 0.f;
#pragma unroll
            for (int tt = 0; tt < 4; ++tt) {
                short8 kf = *(const short8*)&Ks[((2 * tt + half) * 64 + kt * 32 + l31) * 8];
                sa = MFMA32(kf, qf[tt], sa);
            }
            // exp2 (log2-domain), bf16 round, consistent l, swizzled b64 write
#pragma unroll
            for (int rg = 0; rg < 4; ++rg) {
                u16 b0 = f2bf(exp2f(sa[rg * 4 + 0]));
                u16 b1 = f2bf(exp2f(sa[rg * 4 + 1]));
                u16 b2 = f2bf(exp2f(sa[rg * 4 + 2]));
                u16 b3 = f2bf(exp2f(sa[rg * 4 + 3]));
                lp += (bf2f(b0) + bf2f(b1)) + (bf2f(b2) + bf2f(b3));
                bf16x4 pk = {(short)b0, (short)b1, (short)b2, (short)b3};
                const int u = kt * 8 + rg * 2 + half; // logical 8B unit
                *(bf16x4*)&Ps[pbase + (u ^ sw) * 4] = pk;
            }
        }

        // ---- PV phase: O^T += V^T @ P (own-wave P; DS pipe is in-order) ----
#pragma unroll
        for (int k2 = 0; k2 < 4; ++k2) {
            const int u0 = k2 * 4 + half * 2;
            bf16x4 lo = *(const bf16x4*)&Ps[pbase + ((u0 + 0) ^ sw) * 4];
            bf16x4 hi = *(const bf16x4*)&Ps[pbase + ((u0 + 1) ^ sw) * 4];
            short8 pf = __builtin_shufflevector(lo, hi, 0, 1, 2, 3, 4, 5, 6, 7);
#pragma unroll
            for (int dt = 0; dt < 2; ++dt) {
                short8 vf = *(const short8*)&Vs[((2 * k2 + half) * 64 + dt * 32 + l31) * 8];
                o[dt] = MFMA32(vf, pf, o[dt]);
            }
        }
    }

    // final l reduction (halves hold disjoint key subsets) and output
    const float invl = 1.f / (lp + __shfl_xor(lp, 32, 64));
    u16* ob = AO + (size_t)(b * SEQ + qb + l31) * NDIM + h * HD;
#pragma unroll
    for (int dt = 0; dt < 2; ++dt)
#pragma unroll
        for (int rg = 0; rg < 4; ++rg) {
            bf16x4 ok = {(short)f2bf(o[dt][rg * 4 + 0] * invl),
                         (short)f2bf(o[dt][rg * 4 + 1] * invl),
                         (short)f2bf(o[dt][rg * 4 + 2] * invl),
                         (short)f2bf(o[dt][rg * 4 + 3] * invl)};
            *(bf16x4*)(ob + dt * 32 + rg * 8 + half * 4) = ok;
        }
}

// ---------------------------------------------------------------------------
extern "C" void kernel_launch(void* const* d_in, const int* in_sizes, int n_in,
                              void* d_out, int out_size, void* d_ws, size_t ws_size,
                              hipStream_t stream) {
    const float* x    = (const float*)d_in[0];
    const float* Wq   = (const float*)d_in[1];
    const float* Wk   = (const float*)d_in[2];
    const float* Wv   = (const float*)d_in[3];
    const float* Wo   = (const float*)d_in[4];
    const float* s_qk = (const float*)d_in[5];
    float* out = (float*)d_out;

    char* w = (char*)d_ws;
    const size_t TE = (size_t)MROWS * NDIM;
    u16* xb   = (u16*)w;                    w += TE * 2;
    u16* Wqkv = (u16*)w;                    w += (size_t)3 * NDIM * NDIM * 2;
    u16* Wob  = (u16*)w;                    w += (size_t)NDIM * NDIM * 2;
    u16* Qh   = (u16*)w;                    w += TE * 2;
    u16* Kh   = (u16*)w;                    w += TE * 2;
    u16* Vt   = (u16*)w;                    w += TE * 2;
    u16* ao   = (u16*)w;

    castall<<<6144 + 4 * 576, 256, 0, stream>>>(x, Wq, Wk, Wv, Wo, xb, Wqkv, Wob);

    // Fused QKV projection (1D grid, XCD-stripe swizzle): NX = 2304/128 = 18
    gemm_bf16<2><<<18 * 64, 256, 0, stream>>>(
        xb, Wqkv, (void*)Vt, 2304, s_qk, Qh, Kh, 18);

    attn_mfma<<<dim3(SEQ / 128, NHEADS, BATCH), 256, 0, stream>>>(Qh, Kh, Vt, ao);

    // Output projection: NX = 768/128 = 6
    gemm_bf16<0><<<6 * 64, 256, 0, stream>>>(
        ao, Wob, out, NDIM, nullptr, nullptr, nullptr, 6);
}

// Round 9
// 249.371 us; speedup vs baseline: 1.0307x; 1.0307x over previous
//
#include <hip/hip_runtime.h>
#include <hip/hip_bf16.h>
#include <math.h>

#define NDIM 768
#define NHEADS 12
#define HD 64
#define SEQ 1024
#define BATCH 8
#define MROWS (BATCH * SEQ)          // 8192
#define SQRT_DIM 27.712812921102035f // 1/SCALE_PARAM_INIT
#define LOG2E 1.4426950408889634f

typedef unsigned short u16;
typedef unsigned int u32;
typedef __attribute__((ext_vector_type(8))) short short8;   // 8 bf16 = 4 VGPRs
typedef __attribute__((ext_vector_type(4))) short bf16x4;   // 4 bf16 = 2 VGPRs
typedef __attribute__((ext_vector_type(4))) float f32x4;
typedef __attribute__((ext_vector_type(16))) float f32x16;

#define MFMA16(a, b, c) __builtin_amdgcn_mfma_f32_16x16x32_bf16(a, b, c, 0, 0, 0)
#define MFMA32(a, b, c) __builtin_amdgcn_mfma_f32_32x32x16_bf16(a, b, c, 0, 0, 0)

__device__ inline u16 f2bf(float f) {
    __hip_bfloat16 h = __float2bfloat16(f);
    return *reinterpret_cast<u16*>(&h);
}
__device__ inline float bf2f(u16 u) {
    u32 w = ((u32)u) << 16;
    return __builtin_bit_cast(float, w);
}

// async 16B global->LDS. LDS dest is wave-uniform base; HW adds lane*16.
__device__ inline void gl2lds16(const void* g, void* l) {
    __builtin_amdgcn_global_load_lds((const __attribute__((address_space(1))) void*)g,
                                     (__attribute__((address_space(3))) void*)l, 16, 0, 0);
}

// ---------------------------------------------------------------------------
// One fused cast kernel: x (6144 blocks) + Wq/Wk/Wv -> Wqkv, Wo -> Wob.
// ---------------------------------------------------------------------------
__global__ __launch_bounds__(256) void castall(const float* __restrict__ x,
                                               const float* __restrict__ Wq,
                                               const float* __restrict__ Wk,
                                               const float* __restrict__ Wv,
                                               const float* __restrict__ Wo,
                                               u16* __restrict__ xb,
                                               u16* __restrict__ Wqkv,
                                               u16* __restrict__ Wob) {
    const int WB = (NDIM * NDIM) / 1024; // 576 blocks per weight
    int blk = blockIdx.x;
    const float* s;
    u16* d;
    int base;
    if (blk < 6144) {
        s = x; d = xb; base = blk * 1024;
    } else {
        int wsel = (blk - 6144) / WB, r = (blk - 6144) % WB;
        base = r * 1024;
        if (wsel == 0)      { s = Wq; d = Wqkv; }
        else if (wsel == 1) { s = Wk; d = Wqkv + NDIM * NDIM; }
        else if (wsel == 2) { s = Wv; d = Wqkv + 2 * NDIM * NDIM; }
        else                { s = Wo; d = Wob; }
    }
    int i = base + threadIdx.x * 4;
    float4 v = *(const float4*)(s + i);
    d[i] = f2bf(v.x); d[i + 1] = f2bf(v.y); d[i + 2] = f2bf(v.z); d[i + 3] = f2bf(v.w);
}

// ---------------------------------------------------------------------------
// bf16 MFMA GEMM: C = A[M,768] @ B[N,768]^T, fp32 accum. 128x128 tile,
// DOUBLE-BUFFERED BK=32 pipeline, one __syncthreads per iter:
//   stage(0) ; loop k: { sync ; stage(k+1 -> other buf) ; compute(k) }
// The barrier's vmcnt(0) drains loads issued one full compute phase earlier
// (~400 cyc of MFMA+ds_read in flight) instead of loads issued immediately
// before — the cp.async-style overlap the 2-barrier structure can't express.
// (m98 disasm: compiler emits vmcnt(0) only at barriers, never before
// ds_read, so compute-k ds_reads proceed while buffer-k+1 loads fly.)
// Chunk-transposed LDS (slot = kc*128+row); fragment reads conflict-free.
// 1D grid, XCD-stripe swizzle: blk&7 = XCD owns a contiguous 1024-row stripe.
// EPI 0: fp32 row-major C.
// EPI 2: fused QKV epilogue (N=2304): per-64-col head group —
//   groups 0..11  = q: cosine-norm + s_eff*8*log2e -> Qdst [b,h,tok,64]
//   groups 12..23 = k: cosine-norm + s_eff         -> Kdst [b,h,tok,64]
//   groups 24..35 = v: bf16 transposed             -> C as Vt [b,h,d,tok]
// ---------------------------------------------------------------------------
template <int EPI>
__global__ __launch_bounds__(256) void gemm_bf16(const u16* __restrict__ A,
                                                 const u16* __restrict__ B,
                                                 void* __restrict__ C, int N,
                                                 const float* __restrict__ s_qk,
                                                 u16* __restrict__ Qdst,
                                                 u16* __restrict__ Kdst,
                                                 int NX) {
    constexpr int K = NDIM;
    constexpr int NKT = K / 32; // 24 K-tiles
    __shared__ __align__(16) u16 As[2][4096]; // 8 KB per buffer
    __shared__ __align__(16) u16 Bs[2][4096];
    const int t = threadIdx.x;
    const int wave = t >> 6, lane = t & 63;
    const int quad = lane >> 4, l16 = lane & 15;
    const int wx = (wave & 1) * 64, wy = (wave >> 1) * 64;
    const int blk = blockIdx.x;
    const int xcd = blk & 7, local = blk >> 3;
    const int bm = (xcd * 8 + local / NX) * 128;
    const int bn = (local % NX) * 128;

    f32x4 acc[4][4];
#pragma unroll
    for (int i = 0; i < 4; ++i)
#pragma unroll
        for (int j = 0; j < 4; ++j) acc[i][j] = (f32x4){0.f, 0.f, 0.f, 0.f};

    // staging: 512 slots x 16B per buffer; per wave 2 issues A + 2 issues B
    auto stage = [&](int k0, int bsel) {
#pragma unroll
        for (int it = 0; it < 2; ++it) {
            const int cb = it * 256 + wave * 64; // slot base (64-aligned)
            const int kc = cb >> 7;              // 16B chunk 0..3
            const int row = (cb & 127) + lane;
            gl2lds16(A + (size_t)(bm + row) * K + k0 + kc * 8,
                     (char*)As[bsel] + cb * 16);
            gl2lds16(B + (size_t)(bn + row) * K + k0 + kc * 8,
                     (char*)Bs[bsel] + cb * 16);
        }
    };

    stage(0, 0);
#pragma unroll
    for (int kt = 0; kt < NKT; ++kt) {
        __syncthreads(); // drains tile-kt loads (issued one compute phase ago)
        if (kt + 1 < NKT) stage((kt + 1) * 32, (kt + 1) & 1);
        const int b = kt & 1;
        short8 af[4], bfr[4];
#pragma unroll
        for (int i = 0; i < 4; ++i)
            af[i] = *(const short8*)&As[b][(quad * 128 + wy + i * 16 + l16) * 8];
#pragma unroll
        for (int j = 0; j < 4; ++j)
            bfr[j] = *(const short8*)&Bs[b][(quad * 128 + wx + j * 16 + l16) * 8];
#pragma unroll
        for (int i = 0; i < 4; ++i)
#pragma unroll
            for (int j = 0; j < 4; ++j) acc[i][j] = MFMA16(af[i], bfr[j], acc[i][j]);
    }

    if constexpr (EPI == 0) {
#pragma unroll
        for (int i = 0; i < 4; ++i)
#pragma unroll
            for (int j = 0; j < 4; ++j)
#pragma unroll
                for (int r = 0; r < 4; ++r) {
                    const int row = bm + wy + i * 16 + quad * 4 + r;
                    const int col = bn + wx + j * 16 + l16;
                    ((float*)C)[(size_t)row * N + col] = acc[i][j][r];
                }
    } else {
        const int cg = (bn + wx) >> 6; // 0..35
        if (cg >= 2 * NHEADS) {
            // V path: transposed bf16 write into Vt = C
            const int h = cg - 2 * NHEADS;
#pragma unroll
            for (int i = 0; i < 4; ++i)
#pragma unroll
                for (int j = 0; j < 4; ++j)
#pragma unroll
                    for (int r = 0; r < 4; ++r) {
                        const int row = bm + wy + i * 16 + quad * 4 + r; // token
                        const int dd = j * 16 + l16;
                        const int b = row >> 10, n = row & 1023;
                        ((u16*)C)[(((size_t)(b * NHEADS + h) * HD + dd) << 10) + n] =
                            f2bf(acc[i][j][r]);
                    }
        } else {
            const bool isq = cg < NHEADS;
            const int h = isq ? cg : cg - NHEADS;
            u16* dst = isq ? Qdst : Kdst;
            const float ex = isq ? 8.f * LOG2E : 1.f;
            float sq[4];
#pragma unroll
            for (int j = 0; j < 4; ++j)
                sq[j] = s_qk[h * HD + j * 16 + l16] * SQRT_DIM * ex;
#pragma unroll
            for (int i = 0; i < 4; ++i)
#pragma unroll
                for (int r = 0; r < 4; ++r) {
                    float ss = 0.f;
#pragma unroll
                    for (int j = 0; j < 4; ++j) ss += acc[i][j][r] * acc[i][j][r];
                    ss += __shfl_xor(ss, 1, 64);
                    ss += __shfl_xor(ss, 2, 64);
                    ss += __shfl_xor(ss, 4, 64);
                    ss += __shfl_xor(ss, 8, 64);
                    float inv = 1.f / fmaxf(sqrtf(ss), 1e-6f);
                    const int row = bm + wy + i * 16 + quad * 4 + r;
                    const int b = row >> 10, tok = row & 1023;
                    u16* o = dst + ((size_t)(b * NHEADS + h) * SEQ + tok) * HD;
#pragma unroll
                    for (int j = 0; j < 4; ++j)
                        o[j * 16 + l16] = f2bf(acc[i][j][r] * sq[j] * inv);
                }
        }
    }
}

// ---------------------------------------------------------------------------
// MFMA flash attention, 32x32x16, no-max softmax. 256 threads = 4 waves;
// each wave owns 32 queries -> block = 128 queries; streams 64-key tiles.
//   S^T = MFMA(A=K, B=Q): D col = query, consecutive regs = consecutive keys.
//   O^T = MFMA(A=V^T, B=P).
// P buffer: row stride 64 u16 (128 B), XOR-swizzled at 8B-unit granularity
// (phys_unit = u ^ (row & 15)) -> b64 writes and reads conflict-free.
// Qh/Kh: [b,h,tok,64] bf16 (q pre-scaled by 8*log2e), Vt: [b,h,d,tok] bf16.
// l accumulated from bf16-rounded p (numerator/denominator errors cancel).
// ---------------------------------------------------------------------------
__global__ __launch_bounds__(256) void attn_mfma(const u16* __restrict__ Qh,
                                                 const u16* __restrict__ Kh,
                                                 const u16* __restrict__ Vt,
                                                 u16* __restrict__ AO) {
    __shared__ __align__(16) u16 Ks[512 * 8];   // slot = dimchunk*64 + key
    __shared__ __align__(16) u16 Vs[512 * 8];   // slot = keychunk*64 + d
    __shared__ __align__(16) u16 Ps[4 * 32 * 64]; // [wave][qrow][64], swizzled

    const int t = threadIdx.x;
    const int wave = t >> 6, lane = t & 63;
    const int l31 = lane & 31, half = lane >> 5;
    const int b = blockIdx.z, h = blockIdx.y, q0 = blockIdx.x * 128;
    const int bh = b * NHEADS + h;
    const u16* Kb = Kh + (size_t)bh * SEQ * HD;
    const u16* Vb = Vt + (size_t)bh * HD * SEQ;
    const int qb = q0 + wave * 32;
    const int pbase = wave * 2048 + l31 * 64; // this lane's P row (u16 idx)
    const int sw = (l31 & 15);                // XOR key for 8B units

    // Q fragments (B-operand: n = query = l31, k = tt*16 + half*8 + j)
    short8 qf[4];
#pragma unroll
    for (int tt = 0; tt < 4; ++tt)
        qf[tt] = *(const short8*)(Qh + ((size_t)bh * SEQ + qb + l31) * HD +
                                  tt * 16 + half * 8);

    f32x16 o[2]; // [d-tile]
#pragma unroll
    for (int dt = 0; dt < 2; ++dt)
#pragma unroll
        for (int r = 0; r < 16; ++r) o[dt][r] = 0.f;
    float lp = 0.f;

    for (int j0 = 0; j0 < SEQ; j0 += 64) {
        __syncthreads();
#pragma unroll
        for (int it = 0; it < 2; ++it) {
            const int cb = it * 256 + wave * 64; // slot base, wave-uniform
            const int c8 = cb >> 6;              // chunk index 0..7
            gl2lds16(Kb + (size_t)(j0 + lane) * HD + c8 * 8, (char*)Ks + cb * 16);
            gl2lds16(Vb + (size_t)lane * SEQ + j0 + c8 * 8, (char*)Vs + cb * 16);
        }
        asm volatile("s_waitcnt vmcnt(0)" ::: "memory");
        __syncthreads();

        // ---- S^T phase: 64 keys x 32 queries ----
#pragma unroll
        for (int kt = 0; kt < 2; ++kt) {
            f32x16 sa;
#pragma unroll
            for (int r = 0; r < 16; ++r) sa[r] = 0.f;
#pragma unroll
            for (int tt = 0; tt < 4; ++tt) {
                short8 kf = *(const short8*)&Ks[((2 * tt + half) * 64 + kt * 32 + l31) * 8];
                sa = MFMA32(kf, qf[tt], sa);
            }
            // exp2 (log2-domain), bf16 round, consistent l, swizzled b64 write
#pragma unroll
            for (int rg = 0; rg < 4; ++rg) {
                u16 b0 = f2bf(exp2f(sa[rg * 4 + 0]));
                u16 b1 = f2bf(exp2f(sa[rg * 4 + 1]));
                u16 b2 = f2bf(exp2f(sa[rg * 4 + 2]));
                u16 b3 = f2bf(exp2f(sa[rg * 4 + 3]));
                lp += (bf2f(b0) + bf2f(b1)) + (bf2f(b2) + bf2f(b3));
                bf16x4 pk = {(short)b0, (short)b1, (short)b2, (short)b3};
                const int u = kt * 8 + rg * 2 + half; // logical 8B unit
                *(bf16x4*)&Ps[pbase + (u ^ sw) * 4] = pk;
            }
        }

        // ---- PV phase: O^T += V^T @ P (own-wave P; DS pipe is in-order) ----
#pragma unroll
        for (int k2 = 0; k2 < 4; ++k2) {
            const int u0 = k2 * 4 + half * 2;
            bf16x4 lo = *(const bf16x4*)&Ps[pbase + ((u0 + 0) ^ sw) * 4];
            bf16x4 hi = *(const bf16x4*)&Ps[pbase + ((u0 + 1) ^ sw) * 4];
            short8 pf = __builtin_shufflevector(lo, hi, 0, 1, 2, 3, 4, 5, 6, 7);
#pragma unroll
            for (int dt = 0; dt < 2; ++dt) {
                short8 vf = *(const short8*)&Vs[((2 * k2 + half) * 64 + dt * 32 + l31) * 8];
                o[dt] = MFMA32(vf, pf, o[dt]);
            }
        }
    }

    // final l reduction (halves hold disjoint key subsets) and output
    const float invl = 1.f / (lp + __shfl_xor(lp, 32, 64));
    u16* ob = AO + (size_t)(b * SEQ + qb + l31) * NDIM + h * HD;
#pragma unroll
    for (int dt = 0; dt < 2; ++dt)
#pragma unroll
        for (int rg = 0; rg < 4; ++rg) {
            bf16x4 ok = {(short)f2bf(o[dt][rg * 4 + 0] * invl),
                         (short)f2bf(o[dt][rg * 4 + 1] * invl),
                         (short)f2bf(o[dt][rg * 4 + 2] * invl),
                         (short)f2bf(o[dt][rg * 4 + 3] * invl)};
            *(bf16x4*)(ob + dt * 32 + rg * 8 + half * 4) = ok;
        }
}

// ---------------------------------------------------------------------------
extern "C" void kernel_launch(void* const* d_in, const int* in_sizes, int n_in,
                              void* d_out, int out_size, void* d_ws, size_t ws_size,
                              hipStream_t stream) {
    const float* x    = (const float*)d_in[0];
    const float* Wq   = (const float*)d_in[1];
    const float* Wk   = (const float*)d_in[2];
    const float* Wv   = (const float*)d_in[3];
    const float* Wo   = (const float*)d_in[4];
    const float* s_qk = (const float*)d_in[5];
    float* out = (float*)d_out;

    char* w = (char*)d_ws;
    const size_t TE = (size_t)MROWS * NDIM;
    u16* xb   = (u16*)w;                    w += TE * 2;
    u16* Wqkv = (u16*)w;                    w += (size_t)3 * NDIM * NDIM * 2;
    u16* Wob  = (u16*)w;                    w += (size_t)NDIM * NDIM * 2;
    u16* Qh   = (u16*)w;                    w += TE * 2;
    u16* Kh   = (u16*)w;                    w += TE * 2;
    u16* Vt   = (u16*)w;                    w += TE * 2;
    u16* ao   = (u16*)w;

    castall<<<6144 + 4 * 576, 256, 0, stream>>>(x, Wq, Wk, Wv, Wo, xb, Wqkv, Wob);

    // Fused QKV projection (1D grid, XCD-stripe swizzle): NX = 2304/128 = 18
    gemm_bf16<2><<<18 * 64, 256, 0, stream>>>(
        xb, Wqkv, (void*)Vt, 2304, s_qk, Qh, Kh, 18);

    attn_mfma<<<dim3(SEQ / 128, NHEADS, BATCH), 256, 0, stream>>>(Qh, Kh, Vt, ao);

    // Output projection: NX = 768/128 = 6
    gemm_bf16<0><<<6 * 64, 256, 0, stream>>>(
        ao, Wob, out, NDIM, nullptr, nullptr, nullptr, 6);
}

// Round 10
// 205.071 us; speedup vs baseline: 1.2534x; 1.2160x over previous
//
#include <hip/hip_runtime.h>
#include <hip/hip_bf16.h>
#include <math.h>

#define NDIM 768
#define NHEADS 12
#define HD 64
#define SEQ 1024
#define BATCH 8
#define MROWS (BATCH * SEQ)          // 8192
#define SQRT_DIM 27.712812921102035f // 1/SCALE_PARAM_INIT
#define LOG2E 1.4426950408889634f

typedef unsigned short u16;
typedef unsigned int u32;
typedef __attribute__((ext_vector_type(8))) short short8;   // 8 bf16 = 4 VGPRs
typedef __attribute__((ext_vector_type(4))) short bf16x4;   // 4 bf16 = 2 VGPRs
typedef __attribute__((ext_vector_type(4))) float f32x4;
typedef __attribute__((ext_vector_type(16))) float f32x16;

#define MFMA16(a, b, c) __builtin_amdgcn_mfma_f32_16x16x32_bf16(a, b, c, 0, 0, 0)
#define MFMA32(a, b, c) __builtin_amdgcn_mfma_f32_32x32x16_bf16(a, b, c, 0, 0, 0)

__device__ inline u16 f2bf(float f) {
    __hip_bfloat16 h = __float2bfloat16(f);
    return *reinterpret_cast<u16*>(&h);
}
__device__ inline float bf2f(u16 u) {
    u32 w = ((u32)u) << 16;
    return __builtin_bit_cast(float, w);
}

// async 16B global->LDS. LDS dest is wave-uniform base; HW adds lane*16.
__device__ inline void gl2lds16(const void* g, void* l) {
    __builtin_amdgcn_global_load_lds((const __attribute__((address_space(1))) void*)g,
                                     (__attribute__((address_space(3))) void*)l, 16, 0, 0);
}

// ---------------------------------------------------------------------------
// One fused cast kernel: x (6144 blocks) + Wq/Wk/Wv -> Wqkv, Wo -> Wob.
// ---------------------------------------------------------------------------
__global__ __launch_bounds__(256) void castall(const float* __restrict__ x,
                                               const float* __restrict__ Wq,
                                               const float* __restrict__ Wk,
                                               const float* __restrict__ Wv,
                                               const float* __restrict__ Wo,
                                               u16* __restrict__ xb,
                                               u16* __restrict__ Wqkv,
                                               u16* __restrict__ Wob) {
    const int WB = (NDIM * NDIM) / 1024; // 576 blocks per weight
    int blk = blockIdx.x;
    const float* s;
    u16* d;
    int base;
    if (blk < 6144) {
        s = x; d = xb; base = blk * 1024;
    } else {
        int wsel = (blk - 6144) / WB, r = (blk - 6144) % WB;
        base = r * 1024;
        if (wsel == 0)      { s = Wq; d = Wqkv; }
        else if (wsel == 1) { s = Wk; d = Wqkv + NDIM * NDIM; }
        else if (wsel == 2) { s = Wv; d = Wqkv + 2 * NDIM * NDIM; }
        else                { s = Wo; d = Wob; }
    }
    int i = base + threadIdx.x * 4;
    float4 v = *(const float4*)(s + i);
    d[i] = f2bf(v.x); d[i + 1] = f2bf(v.y); d[i + 2] = f2bf(v.z); d[i + 3] = f2bf(v.w);
}

// ---------------------------------------------------------------------------
// bf16 MFMA GEMM: C = A[M,768] @ B[N,768]^T, fp32 accum. 128x128 tile,
// double-buffered BK=32 (one barrier/iter, prefetch-after-barrier).
// LDS slot swizzle S(row,kc) = (row>>4)*64 + (row&15)*4 + (kc ^ ((row>>1)&3)):
//   * each 64-slot gl2lds span covers 16 rows x 4 chunks = 16 FULLY-USED
//     64B cachelines (the old kc-uniform layout touched 64 lines at 25% use —
//     4x L2-transaction amplification, the round-8/9 starvation source);
//   * fragment ds_read_b128 spreads over all 8 bank groups (free).
// 1D grid, XCD-stripe swizzle: blk&7 = XCD owns a contiguous 1024-row stripe.
// EPI 0: fp32 row-major C.
// EPI 2: fused QKV epilogue (N=2304): per-64-col head group —
//   groups 0..11  = q: cosine-norm + s_eff*8*log2e -> Qdst [b,h,tok,64]
//   groups 12..23 = k: cosine-norm + s_eff         -> Kdst [b,h,tok,64]
//   groups 24..35 = v: bf16 transposed             -> C as Vt [b,h,d,tok]
// ---------------------------------------------------------------------------
template <int EPI>
__global__ __launch_bounds__(256) void gemm_bf16(const u16* __restrict__ A,
                                                 const u16* __restrict__ B,
                                                 void* __restrict__ C, int N,
                                                 const float* __restrict__ s_qk,
                                                 u16* __restrict__ Qdst,
                                                 u16* __restrict__ Kdst,
                                                 int NX) {
    constexpr int K = NDIM;
    constexpr int NKT = K / 32; // 24 K-tiles
    __shared__ __align__(16) u16 As[2][4096]; // 8 KB per buffer
    __shared__ __align__(16) u16 Bs[2][4096];
    const int t = threadIdx.x;
    const int wave = t >> 6, lane = t & 63;
    const int quad = lane >> 4, l16 = lane & 15;
    const int wx = (wave & 1) * 64, wy = (wave >> 1) * 64;
    const int blk = blockIdx.x;
    const int xcd = blk & 7, local = blk >> 3;
    const int bm = (xcd * 8 + local / NX) * 128;
    const int bn = (local % NX) * 128;

    f32x4 acc[4][4];
#pragma unroll
    for (int i = 0; i < 4; ++i)
#pragma unroll
        for (int j = 0; j < 4; ++j) acc[i][j] = (f32x4){0.f, 0.f, 0.f, 0.f};

    // staging lane->global mapping (inverse of the slot swizzle):
    const int srl = lane >> 2;                        // row within 16-row span
    const int skc = (lane & 3) ^ ((lane >> 3) & 3);   // chunk 0..3
    auto stage = [&](int k0, int bsel) {
#pragma unroll
        for (int it = 0; it < 2; ++it) {
            const int cb = it * 256 + wave * 64;      // span base (wave-uniform)
            const int row = (cb >> 6) * 16 + srl;     // 0..127
            gl2lds16(A + (size_t)(bm + row) * K + k0 + skc * 8,
                     (char*)As[bsel] + cb * 16);
            gl2lds16(B + (size_t)(bn + row) * K + k0 + skc * 8,
                     (char*)Bs[bsel] + cb * 16);
        }
    };
    // fragment-read swizzle pieces
    const int fxor = (l16 >> 1) & 3;

    stage(0, 0);
#pragma unroll
    for (int kt = 0; kt < NKT; ++kt) {
        __syncthreads(); // drains tile-kt loads (issued one compute phase ago)
        if (kt + 1 < NKT) stage((kt + 1) * 32, (kt + 1) & 1);
        const int b = kt & 1;
        short8 af[4], bfr[4];
#pragma unroll
        for (int i = 0; i < 4; ++i)
            af[i] = *(const short8*)&As[b][
                ((((wy >> 4) + i) * 64 + l16 * 4 + (quad ^ fxor)) * 8)];
#pragma unroll
        for (int j = 0; j < 4; ++j)
            bfr[j] = *(const short8*)&Bs[b][
                ((((wx >> 4) + j) * 64 + l16 * 4 + (quad ^ fxor)) * 8)];
#pragma unroll
        for (int i = 0; i < 4; ++i)
#pragma unroll
            for (int j = 0; j < 4; ++j) acc[i][j] = MFMA16(af[i], bfr[j], acc[i][j]);
    }

    if constexpr (EPI == 0) {
#pragma unroll
        for (int i = 0; i < 4; ++i)
#pragma unroll
            for (int j = 0; j < 4; ++j)
#pragma unroll
                for (int r = 0; r < 4; ++r) {
                    const int row = bm + wy + i * 16 + quad * 4 + r;
                    const int col = bn + wx + j * 16 + l16;
                    ((float*)C)[(size_t)row * N + col] = acc[i][j][r];
                }
    } else {
        const int cg = (bn + wx) >> 6; // 0..35
        if (cg >= 2 * NHEADS) {
            // V path: transposed bf16 write into Vt = C
            const int h = cg - 2 * NHEADS;
#pragma unroll
            for (int i = 0; i < 4; ++i)
#pragma unroll
                for (int j = 0; j < 4; ++j)
#pragma unroll
                    for (int r = 0; r < 4; ++r) {
                        const int row = bm + wy + i * 16 + quad * 4 + r; // token
                        const int dd = j * 16 + l16;
                        const int b = row >> 10, n = row & 1023;
                        ((u16*)C)[(((size_t)(b * NHEADS + h) * HD + dd) << 10) + n] =
                            f2bf(acc[i][j][r]);
                    }
        } else {
            const bool isq = cg < NHEADS;
            const int h = isq ? cg : cg - NHEADS;
            u16* dst = isq ? Qdst : Kdst;
            const float ex = isq ? 8.f * LOG2E : 1.f;
            float sq[4];
#pragma unroll
            for (int j = 0; j < 4; ++j)
                sq[j] = s_qk[h * HD + j * 16 + l16] * SQRT_DIM * ex;
#pragma unroll
            for (int i = 0; i < 4; ++i)
#pragma unroll
                for (int r = 0; r < 4; ++r) {
                    float ss = 0.f;
#pragma unroll
                    for (int j = 0; j < 4; ++j) ss += acc[i][j][r] * acc[i][j][r];
                    ss += __shfl_xor(ss, 1, 64);
                    ss += __shfl_xor(ss, 2, 64);
                    ss += __shfl_xor(ss, 4, 64);
                    ss += __shfl_xor(ss, 8, 64);
                    float inv = 1.f / fmaxf(sqrtf(ss), 1e-6f);
                    const int row = bm + wy + i * 16 + quad * 4 + r;
                    const int b = row >> 10, tok = row & 1023;
                    u16* o = dst + ((size_t)(b * NHEADS + h) * SEQ + tok) * HD;
#pragma unroll
                    for (int j = 0; j < 4; ++j)
                        o[j * 16 + l16] = f2bf(acc[i][j][r] * sq[j] * inv);
                }
        }
    }
}

// ---------------------------------------------------------------------------
// MFMA flash attention, 32x32x16, no-max softmax. 256 threads = 4 waves;
// each wave owns 32 queries -> block = 128 queries; streams 64-key tiles.
//   S^T = MFMA(A=K, B=Q); O^T = MFMA(A=V^T, B=P).
// K/V LDS slot swizzle S(r,c8) = (r>>3)*64 + (r&7)*8 + (c8 ^ (r&7)):
//   each 64-slot gl2lds span = 8 rows x 8 chunks = 16 fully-used cachelines
//   (K rows contiguous -> 1KB dense; V rows stride 2048B -> full 128B/row),
//   vs the old 64-quarter-lines gather. Fragment b128 reads spread over all
//   8 bank groups (free).
// P buffer: row stride 64 u16, XOR-swizzled 8B units (u ^ (row&15)) ->
//   b64 writes/reads conflict-free.
// Qh/Kh: [b,h,tok,64] bf16 (q pre-scaled by 8*log2e), Vt: [b,h,d,tok] bf16.
// l accumulated from bf16-rounded p (numerator/denominator errors cancel).
// ---------------------------------------------------------------------------
__global__ __launch_bounds__(256) void attn_mfma(const u16* __restrict__ Qh,
                                                 const u16* __restrict__ Kh,
                                                 const u16* __restrict__ Vt,
                                                 u16* __restrict__ AO) {
    __shared__ __align__(16) u16 Ks[512 * 8];
    __shared__ __align__(16) u16 Vs[512 * 8];
    __shared__ __align__(16) u16 Ps[4 * 32 * 64]; // [wave][qrow][64], swizzled

    const int t = threadIdx.x;
    const int wave = t >> 6, lane = t & 63;
    const int l31 = lane & 31, half = lane >> 5;
    const int b = blockIdx.z, h = blockIdx.y, q0 = blockIdx.x * 128;
    const int bh = b * NHEADS + h;
    const u16* Kb = Kh + (size_t)bh * SEQ * HD;
    const u16* Vb = Vt + (size_t)bh * HD * SEQ;
    const int qb = q0 + wave * 32;
    const int pbase = wave * 2048 + l31 * 64; // this lane's P row (u16 idx)
    const int sw = (l31 & 15);                // XOR key for 8B units

    // Q fragments (B-operand: n = query = l31, k = tt*16 + half*8 + j)
    short8 qf[4];
#pragma unroll
    for (int tt = 0; tt < 4; ++tt)
        qf[tt] = *(const short8*)(Qh + ((size_t)bh * SEQ + qb + l31) * HD +
                                  tt * 16 + half * 8);

    f32x16 o[2]; // [d-tile]
#pragma unroll
    for (int dt = 0; dt < 2; ++dt)
#pragma unroll
        for (int r = 0; r < 16; ++r) o[dt][r] = 0.f;
    float lp = 0.f;

    // staging lane->global mapping (inverse of slot swizzle)
    const int arl = lane >> 3;            // row within 8-row span
    const int acc8 = (lane & 7) ^ arl;    // chunk 0..7
    // fragment-read bank spread piece
    const int fx8 = l31 & 7;

    for (int j0 = 0; j0 < SEQ; j0 += 64) {
        __syncthreads();
#pragma unroll
        for (int it = 0; it < 2; ++it) {
            const int cb = it * 256 + wave * 64; // span base, wave-uniform
            const int r0 = (cb >> 6) * 8 + arl;  // row 0..63
            gl2lds16(Kb + (size_t)(j0 + r0) * HD + acc8 * 8, (char*)Ks + cb * 16);
            gl2lds16(Vb + (size_t)r0 * SEQ + j0 + acc8 * 8, (char*)Vs + cb * 16);
        }
        asm volatile("s_waitcnt vmcnt(0)" ::: "memory");
        __syncthreads();

        // ---- S^T phase: 64 keys x 32 queries ----
#pragma unroll
        for (int kt = 0; kt < 2; ++kt) {
            f32x16 sa;
#pragma unroll
            for (int r = 0; r < 16; ++r) sa[r] = 0.f;
#pragma unroll
            for (int tt = 0; tt < 4; ++tt) {
                short8 kf = *(const short8*)&Ks[
                    (((kt * 4 + (l31 >> 3)) * 64) + fx8 * 8 +
                     ((2 * tt + half) ^ fx8)) * 8];
                sa = MFMA32(kf, qf[tt], sa);
            }
            // exp2 (log2-domain), bf16 round, consistent l, swizzled b64 write
#pragma unroll
            for (int rg = 0; rg < 4; ++rg) {
                u16 b0 = f2bf(exp2f(sa[rg * 4 + 0]));
                u16 b1 = f2bf(exp2f(sa[rg * 4 + 1]));
                u16 b2 = f2bf(exp2f(sa[rg * 4 + 2]));
                u16 b3 = f2bf(exp2f(sa[rg * 4 + 3]));
                lp += (bf2f(b0) + bf2f(b1)) + (bf2f(b2) + bf2f(b3));
                bf16x4 pk = {(short)b0, (short)b1, (short)b2, (short)b3};
                const int u = kt * 8 + rg * 2 + half; // logical 8B unit
                *(bf16x4*)&Ps[pbase + (u ^ sw) * 4] = pk;
            }
        }

        // ---- PV phase: O^T += V^T @ P (own-wave P; DS pipe is in-order) ----
#pragma unroll
        for (int k2 = 0; k2 < 4; ++k2) {
            const int u0 = k2 * 4 + half * 2;
            bf16x4 lo = *(const bf16x4*)&Ps[pbase + ((u0 + 0) ^ sw) * 4];
            bf16x4 hi = *(const bf16x4*)&Ps[pbase + ((u0 + 1) ^ sw) * 4];
            short8 pf = __builtin_shufflevector(lo, hi, 0, 1, 2, 3, 4, 5, 6, 7);
#pragma unroll
            for (int dt = 0; dt < 2; ++dt) {
                short8 vf = *(const short8*)&Vs[
                    (((dt * 4 + (l31 >> 3)) * 64) + fx8 * 8 +
                     ((2 * k2 + half) ^ fx8)) * 8];
                o[dt] = MFMA32(vf, pf, o[dt]);
            }
        }
    }

    // final l reduction (halves hold disjoint key subsets) and output
    const float invl = 1.f / (lp + __shfl_xor(lp, 32, 64));
    u16* ob = AO + (size_t)(b * SEQ + qb + l31) * NDIM + h * HD;
#pragma unroll
    for (int dt = 0; dt < 2; ++dt)
#pragma unroll
        for (int rg = 0; rg < 4; ++rg) {
            bf16x4 ok = {(short)f2bf(o[dt][rg * 4 + 0] * invl),
                         (short)f2bf(o[dt][rg * 4 + 1] * invl),
                         (short)f2bf(o[dt][rg * 4 + 2] * invl),
                         (short)f2bf(o[dt][rg * 4 + 3] * invl)};
            *(bf16x4*)(ob + dt * 32 + rg * 8 + half * 4) = ok;
        }
}

// ---------------------------------------------------------------------------
extern "C" void kernel_launch(void* const* d_in, const int* in_sizes, int n_in,
                              void* d_out, int out_size, void* d_ws, size_t ws_size,
                              hipStream_t stream) {
    const float* x    = (const float*)d_in[0];
    const float* Wq   = (const float*)d_in[1];
    const float* Wk   = (const float*)d_in[2];
    const float* Wv   = (const float*)d_in[3];
    const float* Wo   = (const float*)d_in[4];
    const float* s_qk = (const float*)d_in[5];
    float* out = (float*)d_out;

    char* w = (char*)d_ws;
    const size_t TE = (size_t)MROWS * NDIM;
    u16* xb   = (u16*)w;                    w += TE * 2;
    u16* Wqkv = (u16*)w;                    w += (size_t)3 * NDIM * NDIM * 2;
    u16* Wob  = (u16*)w;                    w += (size_t)NDIM * NDIM * 2;
    u16* Qh   = (u16*)w;                    w += TE * 2;
    u16* Kh   = (u16*)w;                    w += TE * 2;
    u16* Vt   = (u16*)w;                    w += TE * 2;
    u16* ao   = (u16*)w;

    castall<<<6144 + 4 * 576, 256, 0, stream>>>(x, Wq, Wk, Wv, Wo, xb, Wqkv, Wob);

    // Fused QKV projection (1D grid, XCD-stripe swizzle): NX = 2304/128 = 18
    gemm_bf16<2><<<18 * 64, 256, 0, stream>>>(
        xb, Wqkv, (void*)Vt, 2304, s_qk, Qh, Kh, 18);

    attn_mfma<<<dim3(SEQ / 128, NHEADS, BATCH), 256, 0, stream>>>(Qh, Kh, Vt, ao);

    // Output projection: NX = 768/128 = 6
    gemm_bf16<0><<<6 * 64, 256, 0, stream>>>(
        ao, Wob, out, NDIM, nullptr, nullptr, nullptr, 6);
}

// Round 11
// 198.722 us; speedup vs baseline: 1.2935x; 1.0320x over previous
//
#include <hip/hip_runtime.h>
#include <hip/hip_bf16.h>
#include <math.h>

#define NDIM 768
#define NHEADS 12
#define HD 64
#define SEQ 1024
#define BATCH 8
#define MROWS (BATCH * SEQ)          // 8192
#define SQRT_DIM 27.712812921102035f // 1/SCALE_PARAM_INIT
#define LOG2E 1.4426950408889634f

typedef unsigned short u16;
typedef unsigned int u32;
typedef __attribute__((ext_vector_type(8))) short short8;   // 8 bf16 = 4 VGPRs
typedef __attribute__((ext_vector_type(4))) short bf16x4;   // 4 bf16 = 2 VGPRs
typedef __attribute__((ext_vector_type(4))) float f32x4;
typedef __attribute__((ext_vector_type(16))) float f32x16;

#define MFMA16(a, b, c) __builtin_amdgcn_mfma_f32_16x16x32_bf16(a, b, c, 0, 0, 0)
#define MFMA32(a, b, c) __builtin_amdgcn_mfma_f32_32x32x16_bf16(a, b, c, 0, 0, 0)

#if __has_builtin(__builtin_amdgcn_exp2f)
#define EXP2(x) __builtin_amdgcn_exp2f(x)
#else
#define EXP2(x) exp2f(x)
#endif

__device__ inline u16 f2bf(float f) {
    __hip_bfloat16 h = __float2bfloat16(f);
    return *reinterpret_cast<u16*>(&h);
}

// RNE round a,b to bf16 and pack into one u32 (a = low half). No NaN check —
// callers guarantee finite inputs.
__device__ inline u32 rne_pack(float a, float b) {
    u32 ua = __builtin_bit_cast(u32, a), ub = __builtin_bit_cast(u32, b);
    ua = (ua + 0x7fffu + ((ua >> 16) & 1u)) >> 16;
    ub = (ub + 0x7fffu + ((ub >> 16) & 1u)) >> 16;
    return (ub << 16) | ua;
}

// async 16B global->LDS. LDS dest is wave-uniform base; HW adds lane*16.
__device__ inline void gl2lds16(const void* g, void* l) {
    __builtin_amdgcn_global_load_lds((const __attribute__((address_space(1))) void*)g,
                                     (__attribute__((address_space(3))) void*)l, 16, 0, 0);
}

// ---------------------------------------------------------------------------
// One fused cast kernel: x (6144 blocks) + Wq/Wk/Wv -> Wqkv, Wo -> Wob.
// RNE pair-pack + single 8B store per thread (was 4 scalar u16 stores).
// ---------------------------------------------------------------------------
__global__ __launch_bounds__(256) void castall(const float* __restrict__ x,
                                               const float* __restrict__ Wq,
                                               const float* __restrict__ Wk,
                                               const float* __restrict__ Wv,
                                               const float* __restrict__ Wo,
                                               u16* __restrict__ xb,
                                               u16* __restrict__ Wqkv,
                                               u16* __restrict__ Wob) {
    const int WB = (NDIM * NDIM) / 1024; // 576 blocks per weight
    int blk = blockIdx.x;
    const float* s;
    u16* d;
    int base;
    if (blk < 6144) {
        s = x; d = xb; base = blk * 1024;
    } else {
        int wsel = (blk - 6144) / WB, r = (blk - 6144) % WB;
        base = r * 1024;
        if (wsel == 0)      { s = Wq; d = Wqkv; }
        else if (wsel == 1) { s = Wk; d = Wqkv + NDIM * NDIM; }
        else if (wsel == 2) { s = Wv; d = Wqkv + 2 * NDIM * NDIM; }
        else                { s = Wo; d = Wob; }
    }
    int i = base + threadIdx.x * 4;
    float4 v = *(const float4*)(s + i);
    uint2 o = make_uint2(rne_pack(v.x, v.y), rne_pack(v.z, v.w));
    *(uint2*)(d + i) = o;
}

// ---------------------------------------------------------------------------
// bf16 MFMA GEMM: C = A[M,768] @ B[N,768]^T, fp32 accum. 128x128 tile,
// double-buffered BK=32 (one barrier/iter, prefetch-after-barrier).
// LDS slot swizzle S(row,kc) = (row>>4)*64 + (row&15)*4 + (kc ^ ((row>>1)&3)):
// 16 fully-used 64B cachelines per gl2lds span; fragment reads bank-spread.
// 1D grid, XCD-stripe swizzle. EPI 0: fp32 C. EPI 2: fused QKV epilogue.
// ---------------------------------------------------------------------------
template <int EPI>
__global__ __launch_bounds__(256) void gemm_bf16(const u16* __restrict__ A,
                                                 const u16* __restrict__ B,
                                                 void* __restrict__ C, int N,
                                                 const float* __restrict__ s_qk,
                                                 u16* __restrict__ Qdst,
                                                 u16* __restrict__ Kdst,
                                                 int NX) {
    constexpr int K = NDIM;
    constexpr int NKT = K / 32; // 24 K-tiles
    __shared__ __align__(16) u16 As[2][4096]; // 8 KB per buffer
    __shared__ __align__(16) u16 Bs[2][4096];
    const int t = threadIdx.x;
    const int wave = t >> 6, lane = t & 63;
    const int quad = lane >> 4, l16 = lane & 15;
    const int wx = (wave & 1) * 64, wy = (wave >> 1) * 64;
    const int blk = blockIdx.x;
    const int xcd = blk & 7, local = blk >> 3;
    const int bm = (xcd * 8 + local / NX) * 128;
    const int bn = (local % NX) * 128;

    f32x4 acc[4][4];
#pragma unroll
    for (int i = 0; i < 4; ++i)
#pragma unroll
        for (int j = 0; j < 4; ++j) acc[i][j] = (f32x4){0.f, 0.f, 0.f, 0.f};

    // staging lane->global mapping (inverse of the slot swizzle):
    const int srl = lane >> 2;                        // row within 16-row span
    const int skc = (lane & 3) ^ ((lane >> 3) & 3);   // chunk 0..3
    auto stage = [&](int k0, int bsel) {
#pragma unroll
        for (int it = 0; it < 2; ++it) {
            const int cb = it * 256 + wave * 64;      // span base (wave-uniform)
            const int row = (cb >> 6) * 16 + srl;     // 0..127
            gl2lds16(A + (size_t)(bm + row) * K + k0 + skc * 8,
                     (char*)As[bsel] + cb * 16);
            gl2lds16(B + (size_t)(bn + row) * K + k0 + skc * 8,
                     (char*)Bs[bsel] + cb * 16);
        }
    };
    // fragment-read swizzle pieces
    const int fxor = (l16 >> 1) & 3;

    stage(0, 0);
#pragma unroll
    for (int kt = 0; kt < NKT; ++kt) {
        __syncthreads(); // drains tile-kt loads (issued one compute phase ago)
        if (kt + 1 < NKT) stage((kt + 1) * 32, (kt + 1) & 1);
        const int b = kt & 1;
        short8 af[4], bfr[4];
#pragma unroll
        for (int i = 0; i < 4; ++i)
            af[i] = *(const short8*)&As[b][
                ((((wy >> 4) + i) * 64 + l16 * 4 + (quad ^ fxor)) * 8)];
#pragma unroll
        for (int j = 0; j < 4; ++j)
            bfr[j] = *(const short8*)&Bs[b][
                ((((wx >> 4) + j) * 64 + l16 * 4 + (quad ^ fxor)) * 8)];
#pragma unroll
        for (int i = 0; i < 4; ++i)
#pragma unroll
            for (int j = 0; j < 4; ++j) acc[i][j] = MFMA16(af[i], bfr[j], acc[i][j]);
    }

    if constexpr (EPI == 0) {
#pragma unroll
        for (int i = 0; i < 4; ++i)
#pragma unroll
            for (int j = 0; j < 4; ++j)
#pragma unroll
                for (int r = 0; r < 4; ++r) {
                    const int row = bm + wy + i * 16 + quad * 4 + r;
                    const int col = bn + wx + j * 16 + l16;
                    ((float*)C)[(size_t)row * N + col] = acc[i][j][r];
                }
    } else {
        const int cg = (bn + wx) >> 6; // 0..35
        if (cg >= 2 * NHEADS) {
            // V path: transposed bf16 write into Vt = C
            const int h = cg - 2 * NHEADS;
#pragma unroll
            for (int i = 0; i < 4; ++i)
#pragma unroll
                for (int j = 0; j < 4; ++j)
#pragma unroll
                    for (int r = 0; r < 4; ++r) {
                        const int row = bm + wy + i * 16 + quad * 4 + r; // token
                        const int dd = j * 16 + l16;
                        const int b = row >> 10, n = row & 1023;
                        ((u16*)C)[(((size_t)(b * NHEADS + h) * HD + dd) << 10) + n] =
                            f2bf(acc[i][j][r]);
                    }
        } else {
            const bool isq = cg < NHEADS;
            const int h = isq ? cg : cg - NHEADS;
            u16* dst = isq ? Qdst : Kdst;
            const float ex = isq ? 8.f * LOG2E : 1.f;
            float sq[4];
#pragma unroll
            for (int j = 0; j < 4; ++j)
                sq[j] = s_qk[h * HD + j * 16 + l16] * SQRT_DIM * ex;
#pragma unroll
            for (int i = 0; i < 4; ++i)
#pragma unroll
                for (int r = 0; r < 4; ++r) {
                    float ss = 0.f;
#pragma unroll
                    for (int j = 0; j < 4; ++j) ss += acc[i][j][r] * acc[i][j][r];
                    ss += __shfl_xor(ss, 1, 64);
                    ss += __shfl_xor(ss, 2, 64);
                    ss += __shfl_xor(ss, 4, 64);
                    ss += __shfl_xor(ss, 8, 64);
                    float inv = 1.f / fmaxf(sqrtf(ss), 1e-6f);
                    const int row = bm + wy + i * 16 + quad * 4 + r;
                    const int b = row >> 10, tok = row & 1023;
                    u16* o = dst + ((size_t)(b * NHEADS + h) * SEQ + tok) * HD;
#pragma unroll
                    for (int j = 0; j < 4; ++j)
                        o[j * 16 + l16] = f2bf(acc[i][j][r] * sq[j] * inv);
                }
        }
    }
}

// ---------------------------------------------------------------------------
// MFMA flash attention, 32x32x16, no-max softmax. 256 threads = 4 waves;
// each wave owns 32 queries -> block = 128 queries; streams 64-key tiles.
//   S^T = MFMA(A=K, B=Q); O^T = MFMA(A=V^T, B=P).
// K/V LDS slot swizzle S(r,c8) = (r>>3)*64 + (r&7)*8 + (c8 ^ (r&7)):
// 16 fully-used cachelines per gl2lds span; fragment reads bank-spread.
// P buffer: row stride 64 u16, XOR-swizzled 8B units -> conflict-free b64.
// Softmax scalar path is instruction-dieted: raw v_exp_f32 (bounded logits),
// manual RNE pair-pack (no NaN branch), one uint2 store per 4 values, l
// accumulated from raw fp32 p (RNE is unbiased; validated r3 at 7.3e-4).
// ---------------------------------------------------------------------------
__global__ __launch_bounds__(256) void attn_mfma(const u16* __restrict__ Qh,
                                                 const u16* __restrict__ Kh,
                                                 const u16* __restrict__ Vt,
                                                 u16* __restrict__ AO) {
    __shared__ __align__(16) u16 Ks[512 * 8];
    __shared__ __align__(16) u16 Vs[512 * 8];
    __shared__ __align__(16) u16 Ps[4 * 32 * 64]; // [wave][qrow][64], swizzled

    const int t = threadIdx.x;
    const int wave = t >> 6, lane = t & 63;
    const int l31 = lane & 31, half = lane >> 5;
    const int b = blockIdx.z, h = blockIdx.y, q0 = blockIdx.x * 128;
    const int bh = b * NHEADS + h;
    const u16* Kb = Kh + (size_t)bh * SEQ * HD;
    const u16* Vb = Vt + (size_t)bh * HD * SEQ;
    const int qb = q0 + wave * 32;
    const int pbase = wave * 2048 + l31 * 64; // this lane's P row (u16 idx)
    const int sw = (l31 & 15);                // XOR key for 8B units

    // Q fragments (B-operand: n = query = l31, k = tt*16 + half*8 + j)
    short8 qf[4];
#pragma unroll
    for (int tt = 0; tt < 4; ++tt)
        qf[tt] = *(const short8*)(Qh + ((size_t)bh * SEQ + qb + l31) * HD +
                                  tt * 16 + half * 8);

    f32x16 o[2]; // [d-tile]
#pragma unroll
    for (int dt = 0; dt < 2; ++dt)
#pragma unroll
        for (int r = 0; r < 16; ++r) o[dt][r] = 0.f;
    float lp = 0.f;

    // staging lane->global mapping (inverse of slot swizzle)
    const int arl = lane >> 3;            // row within 8-row span
    const int acc8 = (lane & 7) ^ arl;    // chunk 0..7
    // fragment-read bank spread piece
    const int fx8 = l31 & 7;

    for (int j0 = 0; j0 < SEQ; j0 += 64) {
        __syncthreads();
#pragma unroll
        for (int it = 0; it < 2; ++it) {
            const int cb = it * 256 + wave * 64; // span base, wave-uniform
            const int r0 = (cb >> 6) * 8 + arl;  // row 0..63
            gl2lds16(Kb + (size_t)(j0 + r0) * HD + acc8 * 8, (char*)Ks + cb * 16);
            gl2lds16(Vb + (size_t)r0 * SEQ + j0 + acc8 * 8, (char*)Vs + cb * 16);
        }
        asm volatile("s_waitcnt vmcnt(0)" ::: "memory");
        __syncthreads();

        // ---- S^T phase: 64 keys x 32 queries ----
#pragma unroll
        for (int kt = 0; kt < 2; ++kt) {
            f32x16 sa;
#pragma unroll
            for (int r = 0; r < 16; ++r) sa[r] = 0.f;
#pragma unroll
            for (int tt = 0; tt < 4; ++tt) {
                short8 kf = *(const short8*)&Ks[
                    (((kt * 4 + (l31 >> 3)) * 64) + fx8 * 8 +
                     ((2 * tt + half) ^ fx8)) * 8];
                sa = MFMA32(kf, qf[tt], sa);
            }
            // raw exp2 (log2-domain, bounded), RNE pair-pack, raw-l, b64 write
#pragma unroll
            for (int rg = 0; rg < 4; ++rg) {
                float p0 = EXP2(sa[rg * 4 + 0]);
                float p1 = EXP2(sa[rg * 4 + 1]);
                float p2 = EXP2(sa[rg * 4 + 2]);
                float p3 = EXP2(sa[rg * 4 + 3]);
                lp += (p0 + p1) + (p2 + p3);
                uint2 pk = make_uint2(rne_pack(p0, p1), rne_pack(p2, p3));
                const int u = kt * 8 + rg * 2 + half; // logical 8B unit
                *(uint2*)&Ps[pbase + (u ^ sw) * 4] = pk;
            }
        }

        // ---- PV phase: O^T += V^T @ P (own-wave P; DS pipe is in-order) ----
#pragma unroll
        for (int k2 = 0; k2 < 4; ++k2) {
            const int u0 = k2 * 4 + half * 2;
            bf16x4 lo = *(const bf16x4*)&Ps[pbase + ((u0 + 0) ^ sw) * 4];
            bf16x4 hi = *(const bf16x4*)&Ps[pbase + ((u0 + 1) ^ sw) * 4];
            short8 pf = __builtin_shufflevector(lo, hi, 0, 1, 2, 3, 4, 5, 6, 7);
#pragma unroll
            for (int dt = 0; dt < 2; ++dt) {
                short8 vf = *(const short8*)&Vs[
                    (((dt * 4 + (l31 >> 3)) * 64) + fx8 * 8 +
                     ((2 * k2 + half) ^ fx8)) * 8];
                o[dt] = MFMA32(vf, pf, o[dt]);
            }
        }
    }

    // final l reduction (halves hold disjoint key subsets) and output
    const float invl = 1.f / (lp + __shfl_xor(lp, 32, 64));
    u16* ob = AO + (size_t)(b * SEQ + qb + l31) * NDIM + h * HD;
#pragma unroll
    for (int dt = 0; dt < 2; ++dt)
#pragma unroll
        for (int rg = 0; rg < 4; ++rg) {
            bf16x4 ok = {(short)f2bf(o[dt][rg * 4 + 0] * invl),
                         (short)f2bf(o[dt][rg * 4 + 1] * invl),
                         (short)f2bf(o[dt][rg * 4 + 2] * invl),
                         (short)f2bf(o[dt][rg * 4 + 3] * invl)};
            *(bf16x4*)(ob + dt * 32 + rg * 8 + half * 4) = ok;
        }
}

// ---------------------------------------------------------------------------
extern "C" void kernel_launch(void* const* d_in, const int* in_sizes, int n_in,
                              void* d_out, int out_size, void* d_ws, size_t ws_size,
                              hipStream_t stream) {
    const float* x    = (const float*)d_in[0];
    const float* Wq   = (const float*)d_in[1];
    const float* Wk   = (const float*)d_in[2];
    const float* Wv   = (const float*)d_in[3];
    const float* Wo   = (const float*)d_in[4];
    const float* s_qk = (const float*)d_in[5];
    float* out = (float*)d_out;

    char* w = (char*)d_ws;
    const size_t TE = (size_t)MROWS * NDIM;
    u16* xb   = (u16*)w;                    w += TE * 2;
    u16* Wqkv = (u16*)w;                    w += (size_t)3 * NDIM * NDIM * 2;
    u16* Wob  = (u16*)w;                    w += (size_t)NDIM * NDIM * 2;
    u16* Qh   = (u16*)w;                    w += TE * 2;
    u16* Kh   = (u16*)w;                    w += TE * 2;
    u16* Vt   = (u16*)w;                    w += TE * 2;
    u16* ao   = (u16*)w;

    castall<<<6144 + 4 * 576, 256, 0, stream>>>(x, Wq, Wk, Wv, Wo, xb, Wqkv, Wob);

    // Fused QKV projection (1D grid, XCD-stripe swizzle): NX = 2304/128 = 18
    gemm_bf16<2><<<18 * 64, 256, 0, stream>>>(
        xb, Wqkv, (void*)Vt, 2304, s_qk, Qh, Kh, 18);

    attn_mfma<<<dim3(SEQ / 128, NHEADS, BATCH), 256, 0, stream>>>(Qh, Kh, Vt, ao);

    // Output projection: NX = 768/128 = 6
    gemm_bf16<0><<<6 * 64, 256, 0, stream>>>(
        ao, Wob, out, NDIM, nullptr, nullptr, nullptr, 6);
}